// Round 1
// baseline (711.799 us; speedup 1.0000x reference)
//
#include <hip/hip_runtime.h>
#include <math.h>

// InteractionGate: N=500000 agents, H=64, D=32.
// Algebraic reduction (see analysis): d1 == 0 always, d2[i] = ||goal[i]-position[i]||,
// new_h[i][j] = sigmoid(C[j] + d2[i]*Wd[j] + dot(h[i], W2[j][:])), W2[j][k]=W_fc[j][64+k].
// h_out[idx] = h[idx] (original row). goal_out computed once from scalars.

#define AH 64   // hidden dim H
#define AD 32   // distance embedding dim D

__device__ __forceinline__ float sigmoid_fast(float x) {
    return 1.0f / (1.0f + __expf(-x));
}

// One block, 64 threads. Lane j computes C[j], Wd[j] (-> ws) and goal_out[j] (-> out tail).
__global__ void ig_precompute(
    const float* __restrict__ h,      // N x 64
    const float* __restrict__ ghs,    // 64
    const float* __restrict__ goal,   // N x 2
    const float* __restrict__ pos,    // N x 2
    const float* __restrict__ W_emb,  // 32 x 2
    const float* __restrict__ b_emb,  // 32
    const float* __restrict__ W_fc,   // 64 x 192
    const float* __restrict__ b_fc,   // 64
    const int*   __restrict__ idx_p,
    float* __restrict__ out_goal,     // 64 (= d_out + N*64)
    float* __restrict__ ws)           // C[0:64], Wd[64:128]
{
    const int j = threadIdx.x;        // 0..63
    if (j >= AH) return;
    const int idx = idx_p[0];
    const float* wrow = W_fc + j * (2 * AH + 2 * AD);   // 192 floats

    float c = b_fc[j];
    float g = b_fc[j];
    #pragma unroll 4
    for (int k = 0; k < AH; ++k) {
        const float hk = h[(size_t)idx * AH + k];
        c += hk * wrow[k];
        g += hk * wrow[k];
        g += ghs[k] * wrow[AH + k];
    }

    const float px = pos[(size_t)idx * 2 + 0], py = pos[(size_t)idx * 2 + 1];
    const float gx = goal[(size_t)idx * 2 + 0], gy = goal[(size_t)idx * 2 + 1];
    const float dgx = px - gx, dgy = py - gy;
    const float dg = sqrtf(dgx * dgx + dgy * dgy);

    float wd = 0.0f;
    #pragma unroll 4
    for (int k = 0; k < AD; ++k) {
        const float wsum  = W_emb[k * 2 + 0] + W_emb[k * 2 + 1];
        const float be    = b_emb[k];
        const float w12   = wrow[2 * AH + k] + wrow[2 * AH + AD + k]; // d1e-slot + d2e-slot
        c  += be * w12;                       // d1e == b_emb, plus b_emb part of d2e
        wd += wsum * wrow[2 * AH + AD + k];   // d2 coefficient
        g  += (dg * wsum + be) * w12;         // dge feeds both slots
    }

    ws[j]      = c;
    ws[AH + j] = wd;
    out_goal[j] = sigmoid_fast(g);
}

// Main kernel: one wave per agent-iteration. Lane j holds W2 column j in VGPRs;
// h-row loads are wave-uniform -> scalar loads -> free broadcast into v_fmac.
__global__ __launch_bounds__(256, 4) void ig_main(
    const float* __restrict__ h,      // N x 64
    const float* __restrict__ goal,   // N x 2
    const float* __restrict__ pos,    // N x 2
    const float* __restrict__ W_fc,   // 64 x 192
    const float* __restrict__ ws,     // C, Wd
    const int*   __restrict__ idx_p,
    float* __restrict__ out,          // N x 64
    int N, int total_waves)
{
    const int lane = threadIdx.x & 63;
    const int wid  = blockIdx.x * (blockDim.x >> 6) + (threadIdx.x >> 6);
    const int idx  = idx_p[0];

    // Per-lane constants: W2 column for output `lane` (64 VGPRs).
    const float* wrow = W_fc + lane * (2 * AH + 2 * AD) + AH;
    float w2[AH];
    #pragma unroll
    for (int k = 0; k < AH; k += 4) {
        const float4 v = *(const float4*)(wrow + k);
        w2[k + 0] = v.x; w2[k + 1] = v.y; w2[k + 2] = v.z; w2[k + 3] = v.w;
    }
    const float cj  = ws[lane];
    const float wdj = ws[AH + lane];

    for (int i = wid; i < N; i += total_waves) {
        const size_t rb = (size_t)i * AH;
        // Wave-uniform loads of the whole h row (expect s_load_dwordx4).
        const float4* hrow = (const float4*)(h + rb);
        float a0 = 0.f, a1 = 0.f, a2 = 0.f, a3 = 0.f;
        #pragma unroll
        for (int m = 0; m < AH / 4; ++m) {
            const float4 v = hrow[m];
            a0 += v.x * w2[4 * m + 0];
            a1 += v.y * w2[4 * m + 1];
            a2 += v.z * w2[4 * m + 2];
            a3 += v.w * w2[4 * m + 3];
        }
        // d2 = ||goal[i] - position[i]|| (wave-uniform).
        const float gx = goal[(size_t)i * 2 + 0], gy = goal[(size_t)i * 2 + 1];
        const float px = pos[(size_t)i * 2 + 0],  py = pos[(size_t)i * 2 + 1];
        const float dx = gx - px, dy = gy - py;
        const float d2 = sqrtf(dx * dx + dy * dy);

        const float acc = cj + d2 * wdj + ((a0 + a1) + (a2 + a3));
        float val = sigmoid_fast(acc);
        if (i == idx) val = h[rb + lane];   // row idx keeps original h
        out[rb + lane] = val;               // coalesced 256B per wave
    }
}

extern "C" void kernel_launch(void* const* d_in, const int* in_sizes, int n_in,
                              void* d_out, int out_size, void* d_ws, size_t ws_size,
                              hipStream_t stream) {
    const float* h     = (const float*)d_in[0];
    const float* ghs   = (const float*)d_in[1];
    const float* goal  = (const float*)d_in[2];
    const float* pos   = (const float*)d_in[3];
    const float* W_emb = (const float*)d_in[4];
    const float* b_emb = (const float*)d_in[5];
    const float* W_fc  = (const float*)d_in[6];
    const float* b_fc  = (const float*)d_in[7];
    const int*   idx_p = (const int*)d_in[8];

    const int N = in_sizes[0] / AH;          // 500000
    float* out      = (float*)d_out;         // N*64 h_out, then 64 goal_out
    float* out_goal = out + (size_t)N * AH;
    float* ws       = (float*)d_ws;          // 128 floats

    ig_precompute<<<1, 64, 0, stream>>>(h, ghs, goal, pos, W_emb, b_emb, W_fc, b_fc,
                                        idx_p, out_goal, ws);

    const int blocks = 1280;                 // 5120 waves, ~98 agents each
    const int total_waves = blocks * (256 / 64);
    ig_main<<<blocks, 256, 0, stream>>>(h, goal, pos, W_fc, ws, idx_p, out, N, total_waves);
}

// Round 2
// 266.897 us; speedup vs baseline: 2.6669x; 2.6669x over previous
//
#include <hip/hip_runtime.h>
#include <math.h>

// InteractionGate: N=500000 agents, H=64, D=32.
// Reduction: d1 == 0 always; d2[i] = ||goal[i]-position[i]||;
// new_h[i][j] = sigmoid(C[j] + d2[i]*Wd[j] + dot(h[i], W2[j][:])), W2[j][k]=W_fc[j][64+k].
// h_out[idx] = h[idx]. goal_out (64) computed once.
// R2: bf16 MFMA GEMM formulation. One wave per 16-agent tile iteration,
// persistent grid. W2/C/Wd fragments built once per wave (no per-iter reload —
// R1's VGPR=52 showed the compiler rematerialized W_fc every iteration).

#define AH 64   // hidden dim H
#define AD 32   // distance embedding dim D

typedef __attribute__((ext_vector_type(8))) short bf16x8;
typedef __attribute__((ext_vector_type(4))) float f32x4;

__device__ __forceinline__ float sigmoid_fast(float x) {
    return 1.0f / (1.0f + __expf(-x));
}

// f32 -> bf16 round-to-nearest-even
__device__ __forceinline__ short f2bf(float f) {
    union { float f; unsigned u; } v; v.f = f;
    unsigned r = v.u + 0x7fffu + ((v.u >> 16) & 1u);
    return (short)(r >> 16);
}

// One block, 64 threads. Lane j computes C[j], Wd[j] (-> ws) and goal_out[j].
__global__ void ig_precompute(
    const float* __restrict__ h,      // N x 64
    const float* __restrict__ ghs,    // 64
    const float* __restrict__ goal,   // N x 2
    const float* __restrict__ pos,    // N x 2
    const float* __restrict__ W_emb,  // 32 x 2
    const float* __restrict__ b_emb,  // 32
    const float* __restrict__ W_fc,   // 64 x 192
    const float* __restrict__ b_fc,   // 64
    const int*   __restrict__ idx_p,
    float* __restrict__ out_goal,     // 64 (= d_out + N*64)
    float* __restrict__ ws)           // C[0:64], Wd[64:128]
{
    const int j = threadIdx.x;        // 0..63
    if (j >= AH) return;
    const int idx = idx_p[0];
    const float* wrow = W_fc + j * (2 * AH + 2 * AD);   // 192 floats

    float c = b_fc[j];
    float g = b_fc[j];
    #pragma unroll 4
    for (int k = 0; k < AH; ++k) {
        const float hk = h[(size_t)idx * AH + k];
        c += hk * wrow[k];
        g += hk * wrow[k];
        g += ghs[k] * wrow[AH + k];
    }

    const float px = pos[(size_t)idx * 2 + 0], py = pos[(size_t)idx * 2 + 1];
    const float gx = goal[(size_t)idx * 2 + 0], gy = goal[(size_t)idx * 2 + 1];
    const float dgx = px - gx, dgy = py - gy;
    const float dg = sqrtf(dgx * dgx + dgy * dgy);

    float wd = 0.0f;
    #pragma unroll 4
    for (int k = 0; k < AD; ++k) {
        const float wsum  = W_emb[k * 2 + 0] + W_emb[k * 2 + 1];
        const float be    = b_emb[k];
        const float w12   = wrow[2 * AH + k] + wrow[2 * AH + AD + k];
        c  += be * w12;
        wd += wsum * wrow[2 * AH + AD + k];
        g  += (dg * wsum + be) * w12;
    }

    ws[j]      = c;
    ws[AH + j] = wd;
    out_goal[j] = sigmoid_fast(g);
}

// Main: persistent waves, 16 agents per tile, mfma_f32_16x16x32_bf16.
// A-frag: A[m=lane&15][k=(lane>>4)*8+j]; B-frag: B[k=(lane>>4)*8+j][n=lane&15];
// C/D: col(n)=lane&15, row(m)=(lane>>4)*4+reg.
__global__ __launch_bounds__(256, 4) void ig_mfma(
    const float* __restrict__ h,      // N x 64
    const float* __restrict__ goal,   // N x 2
    const float* __restrict__ pos,    // N x 2
    const float* __restrict__ W_fc,   // 64 x 192
    const float* __restrict__ ws,     // C[0:64], Wd[64:128]
    const int*   __restrict__ idx_p,
    float* __restrict__ out,          // N x 64
    int n_tiles, int total_waves)
{
    const int lane = threadIdx.x & 63;
    const int wid  = blockIdx.x * (blockDim.x >> 6) + (threadIdx.x >> 6);
    const int m15  = lane & 15;
    const int q    = lane >> 4;
    const int idx  = idx_p[0];

    // B fragments (built once per wave): 4 output-groups x 2 k-chunks.
    bf16x8 bfrag[4][2];
    float Cj[4], Wd[4];
    #pragma unroll
    for (int g = 0; g < 4; ++g) {
        const int n = g * 16 + m15;
        Cj[g] = ws[n];
        Wd[g] = ws[AH + n];
        const float* wr = W_fc + (size_t)n * 192 + 64;   // W2[n][:]
        #pragma unroll
        for (int c = 0; c < 2; ++c) {
            const float* p = wr + c * 32 + q * 8;
            const f32x4 v0 = *(const f32x4*)(p);
            const f32x4 v1 = *(const f32x4*)(p + 4);
            bf16x8 b;
            #pragma unroll
            for (int j = 0; j < 4; ++j) { b[j] = f2bf(v0[j]); b[4 + j] = f2bf(v1[j]); }
            bfrag[g][c] = b;
        }
    }

    for (int t = wid; t < n_tiles; t += total_waves) {
        const int a0 = t * 16;
        const int am_ld = a0 + m15;                  // agent this lane loads
        const float* hrow = h + (size_t)am_ld * AH;

        // A: 16 agents x 64 k, fp32 -> 4 dwordx4 per lane (all bytes used once).
        const f32x4 av0 = *(const f32x4*)(hrow + q * 8);
        const f32x4 av1 = *(const f32x4*)(hrow + q * 8 + 4);
        const f32x4 av2 = *(const f32x4*)(hrow + 32 + q * 8);
        const f32x4 av3 = *(const f32x4*)(hrow + 32 + q * 8 + 4);

        // d2 for agent m15 (replicated across q-groups).
        const float gx = goal[(size_t)am_ld * 2 + 0], gy = goal[(size_t)am_ld * 2 + 1];
        const float px = pos[(size_t)am_ld * 2 + 0],  py = pos[(size_t)am_ld * 2 + 1];
        const float dx = gx - px, dy = gy - py;
        const float d2v = sqrtf(dx * dx + dy * dy);

        bf16x8 afrag0, afrag1;
        #pragma unroll
        for (int j = 0; j < 4; ++j) {
            afrag0[j] = f2bf(av0[j]); afrag0[4 + j] = f2bf(av1[j]);
            afrag1[j] = f2bf(av2[j]); afrag1[4 + j] = f2bf(av3[j]);
        }

        f32x4 acc[4];
        #pragma unroll
        for (int g = 0; g < 4; ++g) {
            f32x4 z = {0.f, 0.f, 0.f, 0.f};
            z = __builtin_amdgcn_mfma_f32_16x16x32_bf16(afrag0, bfrag[g][0], z, 0, 0, 0);
            z = __builtin_amdgcn_mfma_f32_16x16x32_bf16(afrag1, bfrag[g][1], z, 0, 0, 0);
            acc[g] = z;
        }

        // Epilogue: lane holds D[m=q*4+r][n=g*16+m15].
        #pragma unroll
        for (int r = 0; r < 4; ++r) {
            const int am = q * 4 + r;                 // agent within tile
            const float d2a = __shfl(d2v, am, 64);    // from lane am (holds d2[am])
            const int agent = a0 + am;
            const size_t rb = (size_t)agent * AH;
            #pragma unroll
            for (int g = 0; g < 4; ++g) {
                float v = acc[g][r] + Cj[g] + d2a * Wd[g];
                v = sigmoid_fast(v);
                if (agent == idx) v = h[rb + g * 16 + m15];  // row idx keeps h
                out[rb + g * 16 + m15] = v;
            }
        }
    }
}

extern "C" void kernel_launch(void* const* d_in, const int* in_sizes, int n_in,
                              void* d_out, int out_size, void* d_ws, size_t ws_size,
                              hipStream_t stream) {
    const float* h     = (const float*)d_in[0];
    const float* ghs   = (const float*)d_in[1];
    const float* goal  = (const float*)d_in[2];
    const float* pos   = (const float*)d_in[3];
    const float* W_emb = (const float*)d_in[4];
    const float* b_emb = (const float*)d_in[5];
    const float* W_fc  = (const float*)d_in[6];
    const float* b_fc  = (const float*)d_in[7];
    const int*   idx_p = (const int*)d_in[8];

    const int N = in_sizes[0] / AH;          // 500000
    float* out      = (float*)d_out;         // N*64 h_out, then 64 goal_out
    float* out_goal = out + (size_t)N * AH;
    float* ws       = (float*)d_ws;          // 128 floats

    ig_precompute<<<1, 64, 0, stream>>>(h, ghs, goal, pos, W_emb, b_emb, W_fc, b_fc,
                                        idx_p, out_goal, ws);

    const int n_tiles = N / 16;              // 31250 (exact)
    const int blocks = 1024;                 // 4 blocks/CU @ 4 waves/EU
    const int total_waves = blocks * (256 / 64);
    ig_mfma<<<blocks, 256, 0, stream>>>(h, goal, pos, W_fc, ws, idx_p, out,
                                        n_tiles, total_waves);
}